// Round 1
// 238.369 us; speedup vs baseline: 1.0252x; 1.0252x over previous
//
#include <hip/hip_runtime.h>

// out[b,h,w,c] = x[b,h,w,c] * mask[h,w,c], all float32.
// mask[h,w,c]=0 iff ANY batch's time strip (ts[b]<=h<ts[b]+8, trand[b,h-ts,w,c]<0.15)
//           or ANY batch's freq strip (fs[b]<=w<fs[b]+8, frand[b,h,w-fs,c]<0.15) hits.
//
// R8: single fused kernel, NO workspace, NO memset. Theory: the measured 244 us
// is ~3 x 80.8 us of 512-MiB fillBufferAligned poison dispatches (likely d_ws
// re-poison); our intrinsic work is ~50 us. Removing all d_ws usage is the
// decisive experiment.
//
// Structure: one block per (row h, batch-chunk). Block builds the 1024-byte
// row mask in LDS (time strips: avg ~1 batch covers a given h; freq strips:
// 64 batches x 8 l x 4 c = 2048 scalars), then streams BCH batches of that row
// through NT loads/stores (x is read exactly once, out written once -> bypass L2).

constexpr int B_ = 64, H_ = 512, W_ = 256, C_ = 4, L_ = 8;
constexpr int WC  = W_ * C_;       // 1024 floats per row
constexpr int HWC = H_ * WC;       // 524288 floats per batch
constexpr int BCH = 16;            // batches per block -> grid (512, 4) = 2048 blocks

typedef float floatx4 __attribute__((ext_vector_type(4)));

__global__ __launch_bounds__(256)
void fused_row(const float* __restrict__ x, const float* __restrict__ trand,
               const float* __restrict__ frand, const int* __restrict__ tstart,
               const int* __restrict__ fstart, float* __restrict__ out) {
    __shared__ unsigned int flagw[WC / 4];   // 256 dwords = 1024 flag bytes (w*4+c)
    __shared__ int ts_s[B_], fs_s[B_];
    const int t  = threadIdx.x;
    const int h  = blockIdx.x;
    const int b0 = blockIdx.y * BCH;

    flagw[t] = 0u;
    if (t < B_) { ts_s[t] = tstart[t]; fs_s[t] = fstart[t]; }
    __syncthreads();

    unsigned char* flags = (unsigned char*)flagw;

    // --- time strips: batches whose [L,W,C] strip covers row h (uniform branch,
    // avg ~1 hit across the 64 iterations).
    for (int b = 0; b < B_; ++b) {
        int l = h - ts_s[b];
        if ((unsigned)l < (unsigned)L_) {
            const floatx4 v = ((const floatx4*)(trand + (size_t)(b * L_ + l) * WC))[t];
            if (v.x < 0.15f) flags[t * 4 + 0] = 1;
            if (v.y < 0.15f) flags[t * 4 + 1] = 1;
            if (v.z < 0.15f) flags[t * 4 + 2] = 1;
            if (v.w < 0.15f) flags[t * 4 + 3] = 1;
        }
    }

    // --- freq strips: for this row h every batch contributes 8(l) x 4(c) values
    // at w = fs[b]+l.  j = jj*256 + t in [0,2048): b=j>>5, l=(j>>2)&7, c=j&3.
    // Benign races: concurrent byte-stores of the same value 1.
#pragma unroll
    for (int jj = 0; jj < 8; ++jj) {
        int j = jj * 256 + t;
        int b = j >> 5, l = (j >> 2) & 7, c = j & 3;
        float v = frand[(size_t)(b * H_ + h) * (L_ * C_) + l * C_ + c];
        if (v < 0.15f) flags[(fs_s[b] + l) * C_ + c] = 1;
    }
    __syncthreads();

    const unsigned fw = flagw[t];            // flag dword for w = t (4 channel bytes)
    const size_t rowoff = (size_t)h * WC;

    // --- streaming apply: x read exactly once, out written once -> nontemporal
    // both ways so the 256 MiB stream doesn't churn L2.
#pragma unroll 4
    for (int bi = 0; bi < BCH; ++bi) {
        const size_t base = (size_t)(b0 + bi) * HWC + rowoff;
        floatx4 v = __builtin_nontemporal_load((const floatx4*)(x + base) + t);
        if (fw & 0x000000ffu) v.x = 0.f;
        if (fw & 0x0000ff00u) v.y = 0.f;
        if (fw & 0x00ff0000u) v.z = 0.f;
        if (fw & 0xff000000u) v.w = 0.f;
        __builtin_nontemporal_store(v, (floatx4*)(out + base) + t);
    }
}

extern "C" void kernel_launch(void* const* d_in, const int* in_sizes, int n_in,
                              void* d_out, int out_size, void* d_ws, size_t ws_size,
                              hipStream_t stream) {
    const float* x  = (const float*)d_in[0];
    const float* tr = (const float*)d_in[1];
    const float* fr = (const float*)d_in[2];
    const int*   ts = (const int*)d_in[3];
    const int*   fs = (const int*)d_in[4];
    float* out = (float*)d_out;

    dim3 grid(H_, B_ / BCH);                 // (512, 4)
    fused_row<<<grid, 256, 0, stream>>>(x, tr, fr, ts, fs, out);
}

// Round 2
// 237.575 us; speedup vs baseline: 1.0286x; 1.0033x over previous
//
#include <hip/hip_runtime.h>

// out[b,h,w,c] = x[b,h,w,c] * mask[h,w,c], all float32.
// mask[h,w,c]=0 iff ANY batch's time strip (ts[b]<=h<ts[b]+8, trand[b,h-ts,w,c]<0.15)
//           or ANY batch's freq strip (fs[b]<=w<fs[b]+8, frand[b,h,w-fs,c]<0.15) hits.
//
// R9: R8 established the ~160-240us of 512-MiB fillBufferAligned poison fills are
// unconditional harness overhead; only our single fused kernel (<79us, not in
// top-5) is controllable. R9 removes the 4x mask-build redundancy: grid (512,1),
// one block per row, BCH=64 -> each row mask built ONCE, frand fetched 4 MiB
// total (was 16), and the mask prologue is amortized over 4x the streaming work.
// First 4 rows of x are prefetched BEFORE the mask phase so frand latency hides
// under the x load latency (registers survive __syncthreads).

constexpr int B_ = 64, H_ = 512, W_ = 256, C_ = 4, L_ = 8;
constexpr int WC  = W_ * C_;       // 1024 floats per row
constexpr int HWC = H_ * WC;       // 524288 floats per batch
constexpr int BCH = 64;            // all batches per block -> grid (512, 1)
constexpr int PF  = 4;             // rows of x prefetched ahead of the mask phase

typedef float floatx4 __attribute__((ext_vector_type(4)));

__global__ __launch_bounds__(256)
void fused_row(const float* __restrict__ x, const float* __restrict__ trand,
               const float* __restrict__ frand, const int* __restrict__ tstart,
               const int* __restrict__ fstart, float* __restrict__ out) {
    __shared__ unsigned int flagw[WC / 4];   // 256 dwords = 1024 flag bytes (w*4+c)
    __shared__ int ts_s[B_], fs_s[B_];
    const int t = threadIdx.x;
    const int h = blockIdx.x;

    flagw[t] = 0u;
    if (t < B_) { ts_s[t] = tstart[t]; fs_s[t] = fstart[t]; }

    // --- prefetch first PF batches' row h of x (issued before any dependent
    // loads; hides the frand/trand latency below).
    floatx4 pre[PF];
#pragma unroll
    for (int bi = 0; bi < PF; ++bi)
        pre[bi] = __builtin_nontemporal_load(
            (const floatx4*)(x + (size_t)bi * HWC + (size_t)h * WC) + t);

    __syncthreads();

    unsigned char* flags = (unsigned char*)flagw;

    // --- time strips: batches whose [L,W,C] strip covers row h (uniform branch,
    // avg ~1 hit across the 64 iterations).
    for (int b = 0; b < B_; ++b) {
        int l = h - ts_s[b];
        if ((unsigned)l < (unsigned)L_) {
            const floatx4 v = ((const floatx4*)(trand + (size_t)(b * L_ + l) * WC))[t];
            if (v.x < 0.15f) flags[t * 4 + 0] = 1;
            if (v.y < 0.15f) flags[t * 4 + 1] = 1;
            if (v.z < 0.15f) flags[t * 4 + 2] = 1;
            if (v.w < 0.15f) flags[t * 4 + 3] = 1;
        }
    }

    // --- freq strips: for this row h every batch contributes 8(l) x 4(c) values
    // at w = fs[b]+l.  j = jj*256 + t in [0,2048): b=j>>5, l=(j>>2)&7, c=j&3.
    // Benign races: concurrent byte-stores of the same value 1.
#pragma unroll
    for (int jj = 0; jj < 8; ++jj) {
        int j = jj * 256 + t;
        int b = j >> 5, l = (j >> 2) & 7, c = j & 3;
        float v = frand[(size_t)(b * H_ + h) * (L_ * C_) + l * C_ + c];
        if (v < 0.15f) flags[(fs_s[b] + l) * C_ + c] = 1;
    }
    __syncthreads();

    const unsigned fw = flagw[t];            // flag dword for w = t (4 channel bytes)
    const size_t rowoff = (size_t)h * WC;

    // --- drain the prefetched rows.
#pragma unroll
    for (int bi = 0; bi < PF; ++bi) {
        floatx4 v = pre[bi];
        if (fw & 0x000000ffu) v.x = 0.f;
        if (fw & 0x0000ff00u) v.y = 0.f;
        if (fw & 0x00ff0000u) v.z = 0.f;
        if (fw & 0xff000000u) v.w = 0.f;
        __builtin_nontemporal_store(v, (floatx4*)(out + (size_t)bi * HWC + rowoff) + t);
    }

    // --- streaming apply: x read exactly once, out written once -> nontemporal
    // both ways so the 256 MiB stream doesn't churn L2.
#pragma unroll 4
    for (int bi = PF; bi < BCH; ++bi) {
        const size_t base = (size_t)bi * HWC + rowoff;
        floatx4 v = __builtin_nontemporal_load((const floatx4*)(x + base) + t);
        if (fw & 0x000000ffu) v.x = 0.f;
        if (fw & 0x0000ff00u) v.y = 0.f;
        if (fw & 0x00ff0000u) v.z = 0.f;
        if (fw & 0xff000000u) v.w = 0.f;
        __builtin_nontemporal_store(v, (floatx4*)(out + base) + t);
    }
}

extern "C" void kernel_launch(void* const* d_in, const int* in_sizes, int n_in,
                              void* d_out, int out_size, void* d_ws, size_t ws_size,
                              hipStream_t stream) {
    const float* x  = (const float*)d_in[0];
    const float* tr = (const float*)d_in[1];
    const float* fr = (const float*)d_in[2];
    const int*   ts = (const int*)d_in[3];
    const int*   fs = (const int*)d_in[4];
    float* out = (float*)d_out;

    fused_row<<<dim3(H_, 1), 256, 0, stream>>>(x, tr, fr, ts, fs, out);
}